// Round 1
// 1124.344 us; speedup vs baseline: 1.3744x; 1.3744x over previous
//
#include <hip/hip_runtime.h>

typedef unsigned short u16;
typedef __bf16 bf16x8 __attribute__((ext_vector_type(8)));
typedef float floatx4 __attribute__((ext_vector_type(4)));

#define OUT_DIM 4096
#define IN_DIM  4096
#define RANK    32
#define MROWS   16384  /* BATCH*SEQ = 4*4096 */
#define SCALE_F 0.5f   /* ALPHA/RANK = 16/32; MULTIPLIER*SCALAR = 1 */

// round-to-nearest-even fp32 -> bf16
__device__ __forceinline__ u16 f2bf(float f) {
  unsigned u = __float_as_uint(f);
  u += 0x7fffu + ((u >> 16) & 1u);
  return (u16)(u >> 16);
}

// async global->LDS, 16B per lane. LDS dest = wave-uniform base + lane*16.
__device__ __forceinline__ void async16(const u16* g, u16* l) {
  __builtin_amdgcn_global_load_lds(
      (const __attribute__((address_space(1))) void*)g,
      (__attribute__((address_space(3))) void*)l,
      16, 0, 0);
}

// ---------------------------------------------------------------------------
// Kernel 1: W_bf16[n,k] = bf16( W0 + 0.5*(w1a@w1b)*(w2a@w2b) )
// grid (OUT_DIM/16, 4): 4-way k-split for 4x block parallelism (was 1 blk/CU).
// ---------------------------------------------------------------------------
__global__ __launch_bounds__(256) void build_w_kernel(
    const float* __restrict__ org, const float* __restrict__ w1a,
    const float* __restrict__ w1b, const float* __restrict__ w2a,
    const float* __restrict__ w2b, u16* __restrict__ Wb) {
  __shared__ float a1[16 * RANK];
  __shared__ float a2[16 * RANK];
  const int tid = threadIdx.x;
  const int row0 = blockIdx.x * 16;
  const int kbase = blockIdx.y * (IN_DIM / 4);

  for (int i = tid; i < 16 * RANK; i += 256) {
    a1[i] = w1a[row0 * RANK + i];
    a2[i] = w2a[row0 * RANK + i];
  }
  __syncthreads();

  for (int kc = kbase; kc < kbase + IN_DIM / 4; kc += 256) {
    const int k = kc + tid;
    float b1[RANK], b2[RANK];
#pragma unroll
    for (int r = 0; r < RANK; ++r) {
      b1[r] = w1b[r * IN_DIM + k];
      b2[r] = w2b[r * IN_DIM + k];
    }
#pragma unroll 4
    for (int i = 0; i < 16; ++i) {
      float s1 = 0.f, s2 = 0.f;
#pragma unroll
      for (int r = 0; r < RANK; ++r) {
        s1 += a1[i * RANK + r] * b1[r];
        s2 += a2[i * RANK + r] * b2[r];
      }
      const int idx = (row0 + i) * IN_DIM + k;
      Wb[idx] = f2bf(org[idx] + SCALE_F * s1 * s2);
    }
  }
}

// ---------------------------------------------------------------------------
// Kernel 2: x fp32 -> bf16, float4 vectorized grid-stride
// ---------------------------------------------------------------------------
__global__ __launch_bounds__(256) void convert_x_kernel(
    const float* __restrict__ x, u16* __restrict__ xb, int n4) {
  const float4* x4 = (const float4*)x;
  ushort4* o4 = (ushort4*)xb;
  int idx = blockIdx.x * blockDim.x + threadIdx.x;
  const int stride = gridDim.x * blockDim.x;
  for (int i = idx; i < n4; i += stride) {
    float4 v = x4[i];
    ushort4 o;
    o.x = f2bf(v.x); o.y = f2bf(v.y); o.z = f2bf(v.z); o.w = f2bf(v.w);
    o4[i] = o;
  }
}

// ---------------------------------------------------------------------------
// Kernel 3: C[M,N] = A[M,K](bf16) @ B[N,K](bf16)^T + bias[N]   (fp32 out)
// 256x256 tile, BK=64, 8 waves (2Mx4N), 4-phase quadrant schedule with
// raw s_barrier + counted vmcnt(8) (T3/T4), st-style XOR LDS swizzle via
// pre-swizzled global source (T2), setprio around MFMA (T5), XCD swizzle (T1).
//
// LDS: 2 K-tile buffers, each A(32KB)+B(32KB). Tile t -> buf[t&1].
// Race-freedom: buf[t&1] is only re-staged (tile t+2) AFTER the barrier that
// ends tile t's last phase (all reads done), and tile t+1's loads are gated
// by vmcnt(8) (8 newer loads = t+2's stay in flight) + publish barrier.
// ---------------------------------------------------------------------------
__global__ __launch_bounds__(512, 2) void gemm_bt_kernel(
    const u16* __restrict__ A, const u16* __restrict__ B,
    const float* __restrict__ bias, float* __restrict__ C) {
  constexpr int K = IN_DIM;
  constexpr int N = OUT_DIM;
  constexpr int NT = K / 64;
  __shared__ alignas(16) u16 lds[4 * 16384];  // buf0A | buf0B | buf1A | buf1B

  const int tid = threadIdx.x;
  const int wave = tid >> 6;
  const int lane = tid & 63;
  const int rl = lane & 15;
  const int quad = lane >> 4;
  const int wm = (wave >> 2) * 128;  // 2 M-waves
  const int wn = (wave & 3) * 64;    // 4 N-waves

  // T1: bijective XCD swizzle (1024 blocks, 1024%8==0 -> simple form valid).
  // 128 consecutive tiles per XCD = 2 N-panels shared by 64 M-blocks.
  const int obid = blockIdx.x;
  const int bid = (obid & 7) * 128 + (obid >> 3);
  const int bm = (bid & 63) * 256;   // M-dim fastest
  const int bn = (bid >> 6) * 256;

  // Staging source offsets (per thread). Linear LDS dest L = k*8192+tid*16;
  // logical offset P = L ^ ((row&7)<<4) (involution, row bits >= 7 unchanged).
  size_t soff[4];
#pragma unroll
  for (int k = 0; k < 4; ++k) {
    const int L = k * 8192 + tid * 16;
    const int P = L ^ (((L >> 7) & 7) << 4);
    soff[k] = (size_t)(P >> 7) * K + (size_t)((P & 127) >> 1);
  }
  const u16* Abase = A + (size_t)bm * K;
  const u16* Bbase = B + (size_t)bn * K;

  // ds_read swizzle: phys = row*128 + ((ks*64 + quad*16) ^ ((rl&7)<<4)).
  // (row&7)==(rl&7) for all frag rows since wm,wn,i*16 are 0 mod 8.
  int swzkq[2];
#pragma unroll
  for (int ks = 0; ks < 2; ++ks)
    swzkq[ks] = ((ks * 64 + quad * 16) ^ ((rl & 7) << 4)) >> 1;  // u16 units
  const int ar0 = wm + rl;
  const int br0 = wn + rl;

  floatx4 acc[8][4] = {};
  bf16x8 aF[4][2];   // current A half (i or 4+i), ks=0/1
  bf16x8 bF[4][2];   // bF[0..1]=B-lo (j=0,1), bF[2..3]=B-hi (j=2,3)

  auto stage = [&](int t, int b) {
    const u16* sA = Abase + t * 64;
    const u16* sB = Bbase + t * 64;
    u16* dA = lds + (b ? 32768 : 0) + wave * 512;
    u16* dB = lds + (b ? 49152 : 16384) + wave * 512;
#pragma unroll
    for (int k = 0; k < 4; ++k) {
      async16(sA + soff[k], dA + k * 4096);
      async16(sB + soff[k], dB + k * 4096);
    }
  };

  // Prologue: tile0 -> buf0, tile1 -> buf1; gate tile0 (8 newest in flight).
  stage(0, 0);
  stage(1, 1);
  asm volatile("s_waitcnt vmcnt(8)" ::: "memory");
  __builtin_amdgcn_s_barrier();

  for (int t = 0; t < NT; ++t) {
    const int b = t & 1;
    const u16* bA = lds + (b ? 32768 : 0);
    const u16* bB = lds + (b ? 49152 : 16384);

    // ---- P0: load A-lo (i=0..3) + B-lo (j=0..1); MFMA Q(0,0)
#pragma unroll
    for (int i = 0; i < 4; ++i)
#pragma unroll
      for (int ks = 0; ks < 2; ++ks)
        aF[i][ks] = *(const bf16x8*)&bA[(ar0 + i * 16) * 64 + swzkq[ks]];
#pragma unroll
    for (int j = 0; j < 2; ++j)
#pragma unroll
      for (int ks = 0; ks < 2; ++ks)
        bF[j][ks] = *(const bf16x8*)&bB[(br0 + j * 16) * 64 + swzkq[ks]];
    __builtin_amdgcn_s_barrier();
    asm volatile("s_waitcnt lgkmcnt(0)" ::: "memory");
    __builtin_amdgcn_s_setprio(1);
#pragma unroll
    for (int i = 0; i < 4; ++i)
#pragma unroll
      for (int j = 0; j < 2; ++j)
#pragma unroll
        for (int ks = 0; ks < 2; ++ks)
          acc[i][j] = __builtin_amdgcn_mfma_f32_16x16x32_bf16(
              aF[i][ks], bF[j][ks], acc[i][j], 0, 0, 0);
    __builtin_amdgcn_s_setprio(0);
    __builtin_amdgcn_s_barrier();

    // ---- P1: load B-hi (j=2,3); MFMA Q(0,1)
#pragma unroll
    for (int j = 0; j < 2; ++j)
#pragma unroll
      for (int ks = 0; ks < 2; ++ks)
        bF[2 + j][ks] = *(const bf16x8*)&bB[(br0 + (2 + j) * 16) * 64 + swzkq[ks]];
    __builtin_amdgcn_s_barrier();
    asm volatile("s_waitcnt lgkmcnt(0)" ::: "memory");
    __builtin_amdgcn_s_setprio(1);
#pragma unroll
    for (int i = 0; i < 4; ++i)
#pragma unroll
      for (int j = 0; j < 2; ++j)
#pragma unroll
        for (int ks = 0; ks < 2; ++ks)
          acc[i][2 + j] = __builtin_amdgcn_mfma_f32_16x16x32_bf16(
              aF[i][ks], bF[2 + j][ks], acc[i][2 + j], 0, 0, 0);
    __builtin_amdgcn_s_setprio(0);
    __builtin_amdgcn_s_barrier();

    // ---- P2: load A-hi (i=4..7); MFMA Q(1,1)
#pragma unroll
    for (int i = 0; i < 4; ++i)
#pragma unroll
      for (int ks = 0; ks < 2; ++ks)
        aF[i][ks] = *(const bf16x8*)&bA[(ar0 + (4 + i) * 16) * 64 + swzkq[ks]];
    __builtin_amdgcn_s_barrier();
    asm volatile("s_waitcnt lgkmcnt(0)" ::: "memory");
    __builtin_amdgcn_s_setprio(1);
#pragma unroll
    for (int i = 0; i < 4; ++i)
#pragma unroll
      for (int j = 0; j < 2; ++j)
#pragma unroll
        for (int ks = 0; ks < 2; ++ks)
          acc[4 + i][2 + j] = __builtin_amdgcn_mfma_f32_16x16x32_bf16(
              aF[i][ks], bF[2 + j][ks], acc[4 + i][2 + j], 0, 0, 0);
    __builtin_amdgcn_s_setprio(0);
    __builtin_amdgcn_s_barrier();

    // ---- P3: no loads (A-hi + retained B-lo); MFMA Q(1,0)
    __builtin_amdgcn_s_setprio(1);
#pragma unroll
    for (int i = 0; i < 4; ++i)
#pragma unroll
      for (int j = 0; j < 2; ++j)
#pragma unroll
        for (int ks = 0; ks < 2; ++ks)
          acc[4 + i][j] = __builtin_amdgcn_mfma_f32_16x16x32_bf16(
              aF[i][ks], bF[j][ks], acc[4 + i][j], 0, 0, 0);
    __builtin_amdgcn_s_setprio(0);
    __builtin_amdgcn_s_barrier();  // all reads of buf[b] complete block-wide

    // ---- Boundary: re-stage drained buffer, counted gate for tile t+1
    if (t + 1 < NT) {
      if (t + 2 < NT) {
        stage(t + 2, b);
        asm volatile("s_waitcnt vmcnt(8)" ::: "memory");  // t+1 landed; t+2 in flight
      } else {
        asm volatile("s_waitcnt vmcnt(0)" ::: "memory");  // tail drain
      }
      __builtin_amdgcn_s_barrier();  // publish
    }
  }

  // Epilogue: C/D layout col=lane&15, row=quad*4+reg (verified m89/m91)
#pragma unroll
  for (int i = 0; i < 8; ++i) {
    const int row0 = bm + wm + i * 16 + quad * 4;
#pragma unroll
    for (int j = 0; j < 4; ++j) {
      const int col = bn + wn + j * 16 + rl;
      const float bv = bias[col];
      float* Cp = C + (size_t)row0 * N + col;
#pragma unroll
      for (int r = 0; r < 4; ++r)
        Cp[(size_t)r * N] = acc[i][j][r] + bv;
    }
  }
}

extern "C" void kernel_launch(void* const* d_in, const int* in_sizes, int n_in,
                              void* d_out, int out_size, void* d_ws, size_t ws_size,
                              hipStream_t stream) {
  const float* x    = (const float*)d_in[0];
  const float* orgW = (const float*)d_in[1];
  const float* bias = (const float*)d_in[2];
  const float* w1a  = (const float*)d_in[3];
  const float* w1b  = (const float*)d_in[4];
  const float* w2a  = (const float*)d_in[5];
  const float* w2b  = (const float*)d_in[6];
  float* out = (float*)d_out;

  // ws layout: [W_bf16: 4096*4096 u16 = 32MB][x_bf16: 16384*4096 u16 = 128MB]
  u16* Wb = (u16*)d_ws;
  u16* Xb = (u16*)d_ws + (size_t)OUT_DIM * IN_DIM;

  build_w_kernel<<<dim3(OUT_DIM / 16, 4), 256, 0, stream>>>(orgW, w1a, w1b, w2a, w2b, Wb);
  convert_x_kernel<<<4096, 256, 0, stream>>>(x, Xb, MROWS * IN_DIM / 4);

  gemm_bt_kernel<<<(MROWS / 256) * (OUT_DIM / 256), 512, 0, stream>>>(Xb, Wb, bias, out);
}